// Round 1
// baseline (822.532 us; speedup 1.0000x reference)
//
#include <hip/hip_runtime.h>
#include <hip/hip_bf16.h>

#define D_MODEL 1024
#define CH      256
#define NT      64
#define TPC     8
#define NCL     8
#define RPB     16      // rows per block
#define BT      256     // threads per block
#define XS      1028    // padded LDS row stride (floats), 16B-aligned
#define EPS_LN  1e-5f

// ---- workspace layout (bytes) ----
#define WS_TPOS 0                       // u32[64][32]  tile sign>0 bits
#define WS_TNEG 8192                    // u32[64][32]  tile sign<0 bits
#define WS_CPOS 16384                   // u32[8][32]   cluster sig>0 bits
#define WS_CNEG 17408                   // u32[8][32]   cluster sig<0 bits
#define WS_CNT  18432                   // u32[64]      histogram
#define WS_W1X  20480                   // float4[256][256] = W1 transposed by k4
#define WS_NEED (20480 + 1048576)

__global__ void prep_kernel(const float* __restrict__ W1,
                            const float* __restrict__ dirs,
                            unsigned* __restrict__ ws, int useT) {
    const int b = blockIdx.x, t = threadIdx.x;
    if (b < 256) {
        if (!useT) return;
        const int k4 = b, j = t;
        const float4* W14 = (const float4*)W1;
        float4 v = W14[j * 256 + k4];
        float4* W1X = (float4*)((char*)ws + WS_W1X);
        W1X[k4 * 256 + j] = v;
    } else if (b < 264) {
        const int tile = (b - 256) * 8 + (t >> 5), w = t & 31;
        unsigned pos = 0, neg = 0;
        for (int i = 0; i < 32; ++i) {
            float v = dirs[tile * D_MODEL + w * 32 + i];
            if (v > 0.f) pos |= 1u << i; else if (v < 0.f) neg |= 1u << i;
        }
        ws[WS_TPOS / 4 + tile * 32 + w] = pos;
        ws[WS_TNEG / 4 + tile * 32 + w] = neg;
    } else if (b == 264) {
        const int c = t >> 5, w = t & 31;
        unsigned pos = 0, neg = 0;
        for (int i = 0; i < 32; ++i) {
            int d = w * 32 + i, s = 0;
            for (int tt = 0; tt < TPC; ++tt) {
                float v = dirs[(c * TPC + tt) * D_MODEL + d];
                s += (v > 0.f) ? 1 : ((v < 0.f) ? -1 : 0);
            }
            if (s > 0) pos |= 1u << i; else if (s < 0) neg |= 1u << i;
        }
        ws[WS_CPOS / 4 + c * 32 + w] = pos;
        ws[WS_CNEG / 4 + c * 32 + w] = neg;
    } else {
        if (t < NT) ws[WS_CNT / 4 + t] = 0u;
    }
}

__launch_bounds__(BT, 2)
__global__ void main_kernel(const float* __restrict__ x,
                            const float* __restrict__ gamma,
                            const float* __restrict__ beta,
                            const float* __restrict__ W1,
                            const float* __restrict__ b1,
                            const float* __restrict__ W2,
                            const float* __restrict__ b2,
                            const float* __restrict__ spline,
                            const float* __restrict__ sscale,
                            const float* __restrict__ dirs,
                            const float* __restrict__ oscale,
                            float* __restrict__ out,
                            float* __restrict__ out_tile,
                            float* __restrict__ out_comp,
                            unsigned* __restrict__ ws, int useT) {
    __shared__ float xn[RPB][XS];
    __shared__ float part[4][RPB][2];
    __shared__ float comp_ab[RPB][2];
    __shared__ float sval_s[RPB];
    __shared__ int   tidx_s[RPB];

    const int tid = threadIdx.x;
    const int wv = tid >> 6, ln = tid & 63;
    const int row0 = blockIdx.x * RPB;

    // ---------- phase 1: load x (kept in regs), LayerNorm -> xn in LDS ----------
    float4 xr[4][4];
    const float4* g4 = (const float4*)gamma;
    const float4* be4 = (const float4*)beta;
    for (int q = 0; q < 4; ++q) {
        const int rl = wv * 4 + q;
        const int row = row0 + rl;
        const float4* xp = (const float4*)(x + (size_t)row * D_MODEL);
        float s = 0.f;
#pragma unroll
        for (int i = 0; i < 4; ++i) {
            xr[q][i] = xp[ln + 64 * i];
            s += xr[q][i].x + xr[q][i].y + xr[q][i].z + xr[q][i].w;
        }
#pragma unroll
        for (int o = 1; o < 64; o <<= 1) s += __shfl_xor(s, o);
        const float mu = s * (1.f / 1024.f);
        float v = 0.f;
#pragma unroll
        for (int i = 0; i < 4; ++i) {
            float dx;
            dx = xr[q][i].x - mu; v += dx * dx;
            dx = xr[q][i].y - mu; v += dx * dx;
            dx = xr[q][i].z - mu; v += dx * dx;
            dx = xr[q][i].w - mu; v += dx * dx;
        }
#pragma unroll
        for (int o = 1; o < 64; o <<= 1) v += __shfl_xor(v, o);
        const float rstd = 1.f / sqrtf(v * (1.f / 1024.f) + EPS_LN);
#pragma unroll
        for (int i = 0; i < 4; ++i) {
            float4 g = g4[ln + 64 * i], bb = be4[ln + 64 * i], o4;
            o4.x = (xr[q][i].x - mu) * rstd * g.x + bb.x;
            o4.y = (xr[q][i].y - mu) * rstd * g.y + bb.y;
            o4.z = (xr[q][i].z - mu) * rstd * g.z + bb.z;
            o4.w = (xr[q][i].w - mu) * rstd * g.w + bb.w;
            *(float4*)&xn[rl][4 * ln + 256 * i] = o4;
        }
    }

    // ---------- phases 2-4: cluster argmax, tile argmax (wave-local rows) ----------
    const unsigned* tpos = ws + WS_TPOS / 4;
    const unsigned* tneg = ws + WS_TNEG / 4;
    const unsigned* cpos = ws + WS_CPOS / 4;
    const unsigned* cneg = ws + WS_CNEG / 4;
    unsigned* counts = ws + WS_CNT / 4;
    const int grp = ln >> 3, seg = ln & 7;

    for (int q = 0; q < 4; ++q) {
        const int rl = wv * 4 + q;
        const int row = row0 + rl;
        float acc = 0.f;
#pragma unroll
        for (int jw = 0; jw < 4; ++jw) {
            const unsigned pw = cpos[grp * 32 + seg * 4 + jw];
            const unsigned nw = cneg[grp * 32 + seg * 4 + jw];
            const int dbase = seg * 128 + jw * 32;
            for (int b2i = 0; b2i < 32; ++b2i) {
                const int bi = (b2i + seg * 4) & 31;     // rotate: avoid LDS bank conflict
                const float xv = xn[rl][dbase + bi];
                const float sg = ((pw >> bi) & 1) ? 1.f : (((nw >> bi) & 1) ? -1.f : 0.f);
                acc = fmaf(xv, sg, acc);
            }
        }
        acc += __shfl_xor(acc, 1); acc += __shfl_xor(acc, 2); acc += __shfl_xor(acc, 4);
        int bc = 0; float bs = -INFINITY;
#pragma unroll
        for (int c = 0; c < NCL; ++c) {
            const float vv = __shfl(acc, c * 8);
            if (vv > bs) { bs = vv; bc = c; }            // strict >: first-index argmax
        }
        float ta = 0.f;
        const int tile = bc * TPC + grp;
#pragma unroll
        for (int jw = 0; jw < 4; ++jw) {
            const unsigned pw = tpos[tile * 32 + seg * 4 + jw];
            const unsigned nw = tneg[tile * 32 + seg * 4 + jw];
            const int dbase = seg * 128 + jw * 32;
            for (int b2i = 0; b2i < 32; ++b2i) {
                const int bi = (b2i + seg * 4) & 31;
                const float xv = xn[rl][dbase + bi];
                const float sg = ((pw >> bi) & 1) ? 1.f : (((nw >> bi) & 1) ? -1.f : 0.f);
                ta = fmaf(xv, sg, ta);
            }
        }
        ta += __shfl_xor(ta, 1); ta += __shfl_xor(ta, 2); ta += __shfl_xor(ta, 4);
        int bt = 0; float bts = -INFINITY;
#pragma unroll
        for (int t = 0; t < TPC; ++t) {
            const float vv = __shfl(ta, t * 8);
            if (vv > bts) { bts = vv; bt = t; }
        }
        const int ti = bc * TPC + bt;
        if (ln == 0) {
            tidx_s[rl] = ti;
            atomicAdd(&counts[ti], 1u);
            out_tile[row] = (float)ti;
        }
    }

    __syncthreads();

    // ---------- phase 5: h[j] = xn @ W1[j] for 16 rows ----------
    const float4* Wp; int sA, sB;
    if (useT) { Wp = (const float4*)((const char*)ws + WS_W1X); sA = 256; sB = 1; }
    else      { Wp = (const float4*)W1;                          sA = 1;   sB = 256; }
    const int j = tid;
    float acc[RPB];
#pragma unroll
    for (int r = 0; r < RPB; ++r) acc[r] = 0.f;
    for (int k4 = 0; k4 < 256; k4 += 2) {
        const float4 wa = Wp[k4 * sA + j * sB];
        const float4 wb = Wp[(k4 + 1) * sA + j * sB];
#pragma unroll
        for (int r = 0; r < RPB; ++r) {
            const float4 xa = *(const float4*)&xn[r][k4 * 4];
            const float4 xb = *(const float4*)&xn[r][k4 * 4 + 4];
            float a = acc[r];
            a = fmaf(xa.x, wa.x, a); a = fmaf(xa.y, wa.y, a);
            a = fmaf(xa.z, wa.z, a); a = fmaf(xa.w, wa.w, a);
            a = fmaf(xb.x, wb.x, a); a = fmaf(xb.y, wb.y, a);
            a = fmaf(xb.z, wb.z, a); a = fmaf(xb.w, wb.w, a);
            acc[r] = a;
        }
    }

    // ---------- phase 6: gelu, W2, tanh ----------
    const float b1j = b1[j];
    const float w20 = W2[j], w21 = W2[CH + j];
    float p0[RPB], p1[RPB];
#pragma unroll
    for (int r = 0; r < RPB; ++r) {
        float h = acc[r] + b1j;
        h = 0.5f * h * (1.f + erff(h * 0.70710678118654752f));
        p0[r] = h * w20; p1[r] = h * w21;
    }
#pragma unroll
    for (int r = 0; r < RPB; ++r) {
        float a0 = p0[r], a1 = p1[r];
#pragma unroll
        for (int o = 1; o < 64; o <<= 1) { a0 += __shfl_xor(a0, o); a1 += __shfl_xor(a1, o); }
        if (ln == 0) { part[wv][r][0] = a0; part[wv][r][1] = a1; }
    }
    __syncthreads();
    if (tid < RPB * 2) {
        const int r = tid >> 1, cc = tid & 1;
        float s = part[0][r][cc] + part[1][r][cc] + part[2][r][cc] + part[3][r][cc];
        s = tanhf(s + b2[cc]);
        comp_ab[r][cc] = s;
        out_comp[(size_t)(row0 + r) * 2 + cc] = s;
    }
    if (tid < RPB) {
        const int r = tid;
        const float a = comp_ab[r][0], b = comp_ab[r][1];
        int ia = (int)((a + 1.0f) / 2.0f * 16.0f);
        int ib = (int)((b + 1.0f) / 2.0f * 16.0f);
        ia = min(max(ia, 0), 15); ib = min(max(ib, 0), 15);
        const int ti = tidx_s[r];
        const float* cp = spline + ((ti * 16 + ia) * 16 + ib) * 3;
        float c0 = cp[0], c1 = cp[1], c2 = cp[2];
        c0 = (c0 > 0.3f) ? 1.f : ((c0 < -0.3f) ? -1.f : 0.f);
        c1 = (c1 > 0.3f) ? 1.f : ((c1 < -0.3f) ? -1.f : 0.f);
        c2 = (c2 > 0.3f) ? 1.f : ((c2 < -0.3f) ? -1.f : 0.f);
        const float la = (a + 1.0f - (float)ia * 0.125f) * 8.0f;
        const float lb = (b + 1.0f - (float)ib * 0.125f) * 8.0f;
        sval_s[r] = (c0 + c1 * la + c2 * lb) * sscale[ti];
    }
    __syncthreads();

    // ---------- phase 8: out = x + output_scale * sval * directions[tile] ----------
    const float os = oscale[0];
    for (int q = 0; q < 4; ++q) {
        const int rl = wv * 4 + q, row = row0 + rl;
        const int ti = tidx_s[rl];
        const float s = sval_s[rl] * os;
        const float4* dp = (const float4*)(dirs + (size_t)ti * D_MODEL);
        float4* op = (float4*)(out + (size_t)row * D_MODEL);
#pragma unroll
        for (int i = 0; i < 4; ++i) {
            const float4 dv = dp[ln + 64 * i];
            const float4 xv = xr[q][i];
            float4 o4;
            o4.x = xv.x + s * dv.x; o4.y = xv.y + s * dv.y;
            o4.z = xv.z + s * dv.z; o4.w = xv.w + s * dv.w;
            op[ln + 64 * i] = o4;
        }
    }
}

__global__ void bal_kernel(const unsigned* __restrict__ counts, float* __restrict__ ob) {
    const int t = threadIdx.x;
    float d = (float)counts[t] - 512.0f;
    float v = d * d;
#pragma unroll
    for (int o = 1; o < 64; o <<= 1) v += __shfl_xor(v, o);
    if (t == 0) ob[0] = (v * (1.f / 64.f)) / 262144.0f * 0.01f;
}

extern "C" void kernel_launch(void* const* d_in, const int* in_sizes, int n_in,
                              void* d_out, int out_size, void* d_ws, size_t ws_size,
                              hipStream_t stream) {
    const float* x      = (const float*)d_in[0];
    const float* gamma  = (const float*)d_in[1];
    const float* beta   = (const float*)d_in[2];
    const float* W1     = (const float*)d_in[3];
    const float* b1     = (const float*)d_in[4];
    const float* W2     = (const float*)d_in[5];
    const float* b2     = (const float*)d_in[6];
    const float* spline = (const float*)d_in[7];
    const float* sscale = (const float*)d_in[8];
    const float* dirs   = (const float*)d_in[9];
    const float* oscale = (const float*)d_in[10];

    const int nrows = in_sizes[0] / D_MODEL;          // 32768
    float* out      = (float*)d_out;
    float* out_tile = out + (size_t)nrows * D_MODEL;
    float* out_comp = out_tile + nrows;
    float* out_bal  = out_comp + (size_t)nrows * 2;

    unsigned* ws = (unsigned*)d_ws;
    const int useT = (ws_size >= (size_t)WS_NEED) ? 1 : 0;

    prep_kernel<<<266, BT, 0, stream>>>(W1, dirs, ws, useT);
    main_kernel<<<nrows / RPB, BT, 0, stream>>>(x, gamma, beta, W1, b1, W2, b2,
                                                spline, sscale, dirs, oscale,
                                                out, out_tile, out_comp, ws, useT);
    bal_kernel<<<1, 64, 0, stream>>>(ws + WS_CNT / 4, out_bal);
}

// Round 2
// 316.509 us; speedup vs baseline: 2.5988x; 2.5988x over previous
//
#include <hip/hip_runtime.h>

#define D_MODEL 1024
#define RPB     16      // rows per block
#define BT      256     // threads per block (4 waves)
#define EPS_LN  1e-5f

typedef _Float16 f16x8 __attribute__((ext_vector_type(8)));
typedef _Float16 f16x4 __attribute__((ext_vector_type(4)));
typedef float    f32x4 __attribute__((ext_vector_type(4)));

// ---- workspace layout (bytes) ----
#define WS_CNT   0                      // u32[64]  histogram
#define WS_CPOS  256                    // u32[8][32] cluster-sig >0 bits
#define WS_CNEG  1280                   // u32[8][32] cluster-sig <0 bits
#define WS_WH    4096                   // f16 frags: W1 hi   [16 tiles][32 ks][64 lanes][8]
#define WS_WL    (4096 + 524288)        // f16 frags: W1 lo
#define WS_SG    (4096 + 1048576)       // f16 frags: sig/csig [5][32][64][8]
#define WS_NEED  (4096 + 1048576 + 163840)

// ---------------- prep: pack W1 / sig fragments, zero counts ----------------
__global__ void prep_kernel(const float* __restrict__ W1,
                            const float* __restrict__ dirs,
                            char* __restrict__ wsb, int useT) {
    const int gid = blockIdx.x * BT + threadIdx.x;
    if (gid < 32768) {                          // W1 fragments (16 tiles x 32 ks x 64 lanes)
        if (!useT) return;
        const int ct = gid >> 11, ks = (gid >> 6) & 31, l = gid & 63;
        const int col = ct * 16 + (l & 15), kb = ks * 32 + ((l >> 4) << 3);
        const float* wp = W1 + col * 1024 + kb;
        f16x8 h, lo;
#pragma unroll
        for (int i = 0; i < 8; ++i) {
            const float v = wp[i];
            const _Float16 hh = (_Float16)v;
            h[i] = hh; lo[i] = (_Float16)(v - (float)hh);
        }
        *(f16x8*)(wsb + WS_WH + (size_t)gid * 16) = h;
        *(f16x8*)(wsb + WS_WL + (size_t)gid * 16) = lo;
    } else if (gid < 43008) {                   // sig fragments (5 tiles x 32 ks x 64 lanes)
        if (!useT) return;
        const int sg = gid - 32768;
        const int st = sg >> 11, ks = (sg >> 6) & 31, l = sg & 63;
        const int c16 = l & 15, kb = ks * 32 + ((l >> 4) << 3);
        f16x8 s;
        if (st < 4) {
            const float* dp = dirs + (st * 16 + c16) * 1024 + kb;
#pragma unroll
            for (int i = 0; i < 8; ++i) {
                const float v = dp[i];
                s[i] = (_Float16)((v > 0.f) ? 1.f : ((v < 0.f) ? -1.f : 0.f));
            }
        } else {
#pragma unroll
            for (int i = 0; i < 8; ++i) {
                if (c16 < 8) {
                    const int k = kb + i; int sum = 0;
                    for (int t = 0; t < 8; ++t) {
                        const float v = dirs[(c16 * 8 + t) * 1024 + k];
                        sum += (v > 0.f) - (v < 0.f);
                    }
                    s[i] = (_Float16)((sum > 0) ? 1.f : ((sum < 0) ? -1.f : 0.f));
                } else s[i] = (_Float16)0.f;
            }
        }
        *(f16x8*)(wsb + WS_SG + (size_t)sg * 16) = s;
    } else if (gid < 43264) {                   // cluster-sig bitmasks (fallback path)
        const int cg = gid - 43008, c = cg >> 5, w = cg & 31;
        unsigned pos = 0, neg = 0;
        for (int i = 0; i < 32; ++i) {
            const int k = w * 32 + i; int sum = 0;
            for (int t = 0; t < 8; ++t) {
                const float v = dirs[(c * 8 + t) * 1024 + k];
                sum += (v > 0.f) - (v < 0.f);
            }
            if (sum > 0) pos |= 1u << i; else if (sum < 0) neg |= 1u << i;
        }
        ((unsigned*)(wsb + WS_CPOS))[c * 32 + w] = pos;
        ((unsigned*)(wsb + WS_CNEG))[c * 32 + w] = neg;
    } else if (gid < 43328) {
        ((unsigned*)(wsb + WS_CNT))[gid - 43264] = 0u;
    }
}

// ---- B-fragment fetch helpers (fast: ws frags; slow: direct from f32) ----
__device__ __forceinline__ void loadW(const char* wsb, const float* __restrict__ W1,
                                      int useT, int ct, int ks, int ln,
                                      f16x8& bh, f16x8& bl) {
    if (useT) {
        const int off = ((ct * 32 + ks) * 64 + ln) * 16;
        bh = *(const f16x8*)(wsb + WS_WH + off);
        bl = *(const f16x8*)(wsb + WS_WL + off);
    } else {
        const int col = ct * 16 + (ln & 15), kb = ks * 32 + ((ln >> 4) << 3);
        const float4 wa = *(const float4*)&W1[col * 1024 + kb];
        const float4 wb = *(const float4*)&W1[col * 1024 + kb + 4];
        const float w[8] = {wa.x, wa.y, wa.z, wa.w, wb.x, wb.y, wb.z, wb.w};
#pragma unroll
        for (int i = 0; i < 8; ++i) {
            const _Float16 hh = (_Float16)w[i];
            bh[i] = hh; bl[i] = (_Float16)(w[i] - (float)hh);
        }
    }
}

__device__ __forceinline__ f16x8 loadS(const char* wsb, const float* __restrict__ dirs,
                                       int useT, int st, int ks, int ln) {
    if (useT) {
        return *(const f16x8*)(wsb + WS_SG + ((st * 32 + ks) * 64 + ln) * 16);
    }
    const int c16 = ln & 15, kb = ks * 32 + ((ln >> 4) << 3);
    f16x8 s;
    if (st < 4) {
        const float* dp = dirs + (st * 16 + c16) * 1024 + kb;
#pragma unroll
        for (int i = 0; i < 8; ++i) {
            const float v = dp[i];
            s[i] = (_Float16)((v > 0.f) ? 1.f : ((v < 0.f) ? -1.f : 0.f));
        }
    } else {
        const unsigned* cp = (const unsigned*)(wsb + WS_CPOS);
        const unsigned* cn = (const unsigned*)(wsb + WS_CNEG);
#pragma unroll
        for (int i = 0; i < 8; ++i) {
            if (c16 < 8) {
                const int k = kb + i;
                const unsigned p = (cp[c16 * 32 + (k >> 5)] >> (k & 31)) & 1u;
                const unsigned n = (cn[c16 * 32 + (k >> 5)] >> (k & 31)) & 1u;
                s[i] = (_Float16)(p ? 1.f : (n ? -1.f : 0.f));
            } else s[i] = (_Float16)0.f;
        }
    }
    return s;
}

__launch_bounds__(BT, 2)
__global__ void main_kernel(const float* __restrict__ x,
                            const float* __restrict__ gamma,
                            const float* __restrict__ beta,
                            const float* __restrict__ W1,
                            const float* __restrict__ b1,
                            const float* __restrict__ W2,
                            const float* __restrict__ b2,
                            const float* __restrict__ spline,
                            const float* __restrict__ sscale,
                            const float* __restrict__ dirs,
                            const float* __restrict__ oscale,
                            float* __restrict__ out,
                            float* __restrict__ out_tile,
                            float* __restrict__ out_comp,
                            char* __restrict__ wsb, int useT) {
    __shared__ __align__(16) _Float16 xh[RPB * 1024];   // hi halves, XOR-swizzled rows
    __shared__ __align__(16) _Float16 xlo[RPB * 1024];  // lo halves
    __shared__ float scores[RPB][80];
    __shared__ float part[4][RPB][2];
    __shared__ float comp_ab[RPB][2];
    __shared__ float sval_s[RPB];
    __shared__ int   tidx_s[RPB];

    const int tid = threadIdx.x, wv = tid >> 6, ln = tid & 63;
    const int row0 = blockIdx.x * RPB;

    // ---------- phase 1: LayerNorm; x kept in regs; xn -> f16 hi/lo in LDS ----------
    float4 xr[4][4];
    const float4* g4 = (const float4*)gamma;
    const float4* be4 = (const float4*)beta;
    for (int q = 0; q < 4; ++q) {
        const int rl = wv * 4 + q;
        const float4* xp = (const float4*)(x + (size_t)(row0 + rl) * D_MODEL);
        float s = 0.f;
#pragma unroll
        for (int i = 0; i < 4; ++i) {
            xr[q][i] = xp[ln + 64 * i];
            s += xr[q][i].x + xr[q][i].y + xr[q][i].z + xr[q][i].w;
        }
#pragma unroll
        for (int o = 1; o < 64; o <<= 1) s += __shfl_xor(s, o);
        const float mu = s * (1.f / 1024.f);
        float v = 0.f;
#pragma unroll
        for (int i = 0; i < 4; ++i) {
            float dx;
            dx = xr[q][i].x - mu; v += dx * dx;
            dx = xr[q][i].y - mu; v += dx * dx;
            dx = xr[q][i].z - mu; v += dx * dx;
            dx = xr[q][i].w - mu; v += dx * dx;
        }
#pragma unroll
        for (int o = 1; o < 64; o <<= 1) v += __shfl_xor(v, o);
        const float rstd = 1.f / sqrtf(v * (1.f / 1024.f) + EPS_LN);
        const int sw = (rl & 7) << 3;              // element-level XOR swizzle
#pragma unroll
        for (int i = 0; i < 4; ++i) {
            const float4 g = g4[ln + 64 * i], bb = be4[ln + 64 * i];
            float o0 = (xr[q][i].x - mu) * rstd * g.x + bb.x;
            float o1 = (xr[q][i].y - mu) * rstd * g.y + bb.y;
            float o2 = (xr[q][i].z - mu) * rstd * g.z + bb.z;
            float o3 = (xr[q][i].w - mu) * rstd * g.w + bb.w;
            f16x4 hv, lv;
            _Float16 t0 = (_Float16)o0; hv[0] = t0; lv[0] = (_Float16)(o0 - (float)t0);
            _Float16 t1 = (_Float16)o1; hv[1] = t1; lv[1] = (_Float16)(o1 - (float)t1);
            _Float16 t2 = (_Float16)o2; hv[2] = t2; lv[2] = (_Float16)(o2 - (float)t2);
            _Float16 t3 = (_Float16)o3; hv[3] = t3; lv[3] = (_Float16)(o3 - (float)t3);
            const int k0 = 4 * (ln + 64 * i);
            const int idx = rl * 1024 + (k0 ^ sw);
            *(f16x4*)&xh[idx]  = hv;
            *(f16x4*)&xlo[idx] = lv;
        }
    }
    __syncthreads();

    // ---------- phase M: MFMA — 16 W1 col-tiles (3 products) + 5 sig tiles (2) ----------
    const int r16 = ln & 15;
    const int kofs = (ln >> 4) << 3;
    const int asw = (r16 & 7) << 3;
    f32x4 acc[6];
#pragma unroll
    for (int i = 0; i < 6; ++i) acc[i] = (f32x4){0.f, 0.f, 0.f, 0.f};

    if (wv < 3) {
        const int ct0 = wv * 5;
        for (int ks = 0; ks < 32; ++ks) {
            const int aidx = r16 * 1024 + ((ks * 32 + kofs) ^ asw);
            const f16x8 ah = *(const f16x8*)&xh[aidx];
            const f16x8 al = *(const f16x8*)&xlo[aidx];
#pragma unroll
            for (int t = 0; t < 5; ++t) {
                f16x8 bh, bl;
                loadW(wsb, W1, useT, ct0 + t, ks, ln, bh, bl);
                acc[t] = __builtin_amdgcn_mfma_f32_16x16x32_f16(ah, bh, acc[t], 0, 0, 0);
                acc[t] = __builtin_amdgcn_mfma_f32_16x16x32_f16(ah, bl, acc[t], 0, 0, 0);
                acc[t] = __builtin_amdgcn_mfma_f32_16x16x32_f16(al, bh, acc[t], 0, 0, 0);
            }
        }
    } else {
        for (int ks = 0; ks < 32; ++ks) {
            const int aidx = r16 * 1024 + ((ks * 32 + kofs) ^ asw);
            const f16x8 ah = *(const f16x8*)&xh[aidx];
            const f16x8 al = *(const f16x8*)&xlo[aidx];
            f16x8 bh, bl;
            loadW(wsb, W1, useT, 15, ks, ln, bh, bl);
            acc[5] = __builtin_amdgcn_mfma_f32_16x16x32_f16(ah, bh, acc[5], 0, 0, 0);
            acc[5] = __builtin_amdgcn_mfma_f32_16x16x32_f16(ah, bl, acc[5], 0, 0, 0);
            acc[5] = __builtin_amdgcn_mfma_f32_16x16x32_f16(al, bh, acc[5], 0, 0, 0);
#pragma unroll
            for (int st = 0; st < 5; ++st) {
                const f16x8 sg = loadS(wsb, dirs, useT, st, ks, ln);
                acc[st] = __builtin_amdgcn_mfma_f32_16x16x32_f16(ah, sg, acc[st], 0, 0, 0);
                acc[st] = __builtin_amdgcn_mfma_f32_16x16x32_f16(al, sg, acc[st], 0, 0, 0);
            }
        }
    }

    // ---------- epilogue: gelu+W2 partials (W1 tiles), score dump (sig tiles) ----------
    float p0s[4] = {0.f, 0.f, 0.f, 0.f}, p1s[4] = {0.f, 0.f, 0.f, 0.f};
    if (wv < 3) {
#pragma unroll
        for (int t = 0; t < 5; ++t) {
            const int col = (wv * 5 + t) * 16 + r16;
            const float b1c = b1[col], w20 = W2[col], w21 = W2[256 + col];
#pragma unroll
            for (int reg = 0; reg < 4; ++reg) {
                const float h = acc[t][reg] + b1c;
                const float g = 0.5f * h * (1.f + erff(h * 0.70710678118654752f));
                p0s[reg] += g * w20; p1s[reg] += g * w21;
            }
        }
    } else {
        const int col = 15 * 16 + r16;
        const float b1c = b1[col], w20 = W2[col], w21 = W2[256 + col];
#pragma unroll
        for (int reg = 0; reg < 4; ++reg) {
            const float h = acc[5][reg] + b1c;
            const float g = 0.5f * h * (1.f + erff(h * 0.70710678118654752f));
            p0s[reg] += g * w20; p1s[reg] += g * w21;
        }
#pragma unroll
        for (int st = 0; st < 5; ++st)
#pragma unroll
            for (int reg = 0; reg < 4; ++reg)
                scores[(ln >> 4) * 4 + reg][st * 16 + r16] = acc[st][reg];
    }
#pragma unroll
    for (int reg = 0; reg < 4; ++reg) {
        float a0 = p0s[reg], a1 = p1s[reg];
        a0 += __shfl_xor(a0, 1); a0 += __shfl_xor(a0, 2);
        a0 += __shfl_xor(a0, 4); a0 += __shfl_xor(a0, 8);
        a1 += __shfl_xor(a1, 1); a1 += __shfl_xor(a1, 2);
        a1 += __shfl_xor(a1, 4); a1 += __shfl_xor(a1, 8);
        if (r16 == 0) {
            const int row = (ln >> 4) * 4 + reg;
            part[wv][row][0] = a0; part[wv][row][1] = a1;
        }
    }
    __syncthreads();

    // ---------- selection (tid<16) and comp finalize (tid 64..95) ----------
    unsigned* cntp = (unsigned*)(wsb + WS_CNT);
    if (tid < 16) {
        const int r = tid;
        int bc = 0; float bs = scores[r][64];
#pragma unroll
        for (int c = 1; c < 8; ++c) { const float v = scores[r][64 + c]; if (v > bs) { bs = v; bc = c; } }
        int bt = 0; float ts = scores[r][bc * 8];
#pragma unroll
        for (int p = 1; p < 8; ++p) { const float v = scores[r][bc * 8 + p]; if (v > ts) { ts = v; bt = p; } }
        const int ti = bc * 8 + bt;
        tidx_s[r] = ti;
        atomicAdd(&cntp[ti], 1u);
        out_tile[row0 + r] = (float)ti;
    } else if (tid >= 64 && tid < 96) {
        const int r = (tid - 64) >> 1, cc = tid & 1;
        float s = part[0][r][cc] + part[1][r][cc] + part[2][r][cc] + part[3][r][cc] + b2[cc];
        s = tanhf(s);
        comp_ab[r][cc] = s;
        out_comp[(size_t)(row0 + r) * 2 + cc] = s;
    }
    __syncthreads();

    // ---------- spline lookup ----------
    if (tid < 16) {
        const int r = tid;
        const float a = comp_ab[r][0], b = comp_ab[r][1];
        int ia = (int)((a + 1.0f) / 2.0f * 16.0f);
        int ib = (int)((b + 1.0f) / 2.0f * 16.0f);
        ia = min(max(ia, 0), 15); ib = min(max(ib, 0), 15);
        const int ti = tidx_s[r];
        const float* cp = spline + ((ti * 16 + ia) * 16 + ib) * 3;
        float c0 = cp[0], c1 = cp[1], c2 = cp[2];
        c0 = (c0 > 0.3f) ? 1.f : ((c0 < -0.3f) ? -1.f : 0.f);
        c1 = (c1 > 0.3f) ? 1.f : ((c1 < -0.3f) ? -1.f : 0.f);
        c2 = (c2 > 0.3f) ? 1.f : ((c2 < -0.3f) ? -1.f : 0.f);
        const float la = (a + 1.0f - (float)ia * 0.125f) * 8.0f;
        const float lb = (b + 1.0f - (float)ib * 0.125f) * 8.0f;
        sval_s[r] = (c0 + c1 * la + c2 * lb) * sscale[ti];
    }
    __syncthreads();

    // ---------- phase 8: out = x + output_scale * sval * directions[tile] ----------
    const float os = oscale[0];
    for (int q = 0; q < 4; ++q) {
        const int rl = wv * 4 + q, row = row0 + rl;
        const int ti = tidx_s[rl];
        const float s = sval_s[rl] * os;
        const float4* dp = (const float4*)(dirs + (size_t)ti * D_MODEL);
        float4* op = (float4*)(out + (size_t)row * D_MODEL);
#pragma unroll
        for (int i = 0; i < 4; ++i) {
            const float4 dv = dp[ln + 64 * i];
            const float4 xv = xr[q][i];
            float4 o4;
            o4.x = xv.x + s * dv.x; o4.y = xv.y + s * dv.y;
            o4.z = xv.z + s * dv.z; o4.w = xv.w + s * dv.w;
            op[ln + 64 * i] = o4;
        }
    }
}

__global__ void bal_kernel(const unsigned* __restrict__ counts, float* __restrict__ ob) {
    const int t = threadIdx.x;
    const float d = (float)counts[t] - 512.0f;
    float v = d * d;
#pragma unroll
    for (int o = 1; o < 64; o <<= 1) v += __shfl_xor(v, o);
    if (t == 0) ob[0] = (v * (1.f / 64.f)) / 262144.0f * 0.01f;
}

extern "C" void kernel_launch(void* const* d_in, const int* in_sizes, int n_in,
                              void* d_out, int out_size, void* d_ws, size_t ws_size,
                              hipStream_t stream) {
    const float* x      = (const float*)d_in[0];
    const float* gamma  = (const float*)d_in[1];
    const float* beta   = (const float*)d_in[2];
    const float* W1     = (const float*)d_in[3];
    const float* b1     = (const float*)d_in[4];
    const float* W2     = (const float*)d_in[5];
    const float* b2     = (const float*)d_in[6];
    const float* spline = (const float*)d_in[7];
    const float* sscale = (const float*)d_in[8];
    const float* dirs   = (const float*)d_in[9];
    const float* oscale = (const float*)d_in[10];

    const int nrows = in_sizes[0] / D_MODEL;          // 32768
    float* out      = (float*)d_out;
    float* out_tile = out + (size_t)nrows * D_MODEL;
    float* out_comp = out_tile + nrows;
    float* out_bal  = out_comp + (size_t)nrows * 2;

    char* wsb = (char*)d_ws;
    const int useT = (ws_size >= (size_t)WS_NEED) ? 1 : 0;

    prep_kernel<<<170, BT, 0, stream>>>(W1, dirs, wsb, useT);
    main_kernel<<<nrows / RPB, BT, 0, stream>>>(x, gamma, beta, W1, b1, W2, b2,
                                                spline, sscale, dirs, oscale,
                                                out, out_tile, out_comp, wsb, useT);
    bal_kernel<<<1, 64, 0, stream>>>((const unsigned*)(wsb + WS_CNT), out_bal);
}

// Round 3
// 230.437 us; speedup vs baseline: 3.5695x; 1.3735x over previous
//
#include <hip/hip_runtime.h>

#define D_MODEL 1024
#define ROWS    32      // rows per block
#define BT      512     // threads per block (8 waves)
#define EPS_LN  1e-5f

typedef _Float16 f16x8 __attribute__((ext_vector_type(8)));
typedef _Float16 f16x4 __attribute__((ext_vector_type(4)));
typedef float    f32x4 __attribute__((ext_vector_type(4)));

// ---- workspace layout (bytes) ----
#define WS_CNT   0                        // u32[64]   histogram
#define WS_B1P   256                      // f32[256]  b1' = b1 + beta @ W1^T
#define WS_CT    1280                     // f32[80]   score offsets (beta dot sig/csig)
#define WS_FH    4096                     // f16x8 [21][32][64]  gamma-folded B hi
#define WS_FL    (4096 + 688128)          // f16x8 [21][32][64]  gamma-folded B lo
#define WS_NEED  (4096 + 2 * 688128)

// tiles 0..15 : W1' columns (16 cols each)   -> gelu/W2 path
// tiles 16..19: gamma*sign(dirs) (64 tiles)  -> tile scores
// tile  20    : gamma*csig (8 cols used)     -> cluster scores

__global__ void prep_kernel(const float* __restrict__ W1,
                            const float* __restrict__ dirs,
                            const float* __restrict__ gamma,
                            const float* __restrict__ beta,
                            const float* __restrict__ b1,
                            char* __restrict__ wsb, int useT) {
    const int b = blockIdx.x, tid = threadIdx.x;
    if (b < 168) {                         // B fragments (21 x 32 x 64 lanes)
        if (!useT) return;
        const int gid = b * 256 + tid;
        const int ct = gid >> 11, ks = (gid >> 6) & 31, l = gid & 63;
        const int c16 = l & 15, kb = ks * 32 + ((l >> 4) << 3);
        f16x8 h, lo;
#pragma unroll
        for (int i = 0; i < 8; ++i) {
            const int k = kb + i;
            const float g = gamma[k];
            float v;
            if (ct < 16) {
                v = g * W1[(ct * 16 + c16) * 1024 + k];
            } else if (ct < 20) {
                const float d = dirs[((ct - 16) * 16 + c16) * 1024 + k];
                v = g * (float)((d > 0.f) - (d < 0.f));
            } else {
                if (c16 < 8) {
                    int s = 0;
                    for (int t = 0; t < 8; ++t) {
                        const float d = dirs[(c16 * 8 + t) * 1024 + k];
                        s += (d > 0.f) - (d < 0.f);
                    }
                    v = g * (float)((s > 0) - (s < 0));
                } else v = 0.f;
            }
            const _Float16 hh = (_Float16)v;
            h[i] = hh; lo[i] = (_Float16)(v - (float)hh);
        }
        *(f16x8*)(wsb + WS_FH + (size_t)gid * 16) = h;
        *(f16x8*)(wsb + WS_FL + (size_t)gid * 16) = lo;
    } else if (b < 184) {                  // b1' (16 cols per block)
        __shared__ float red[256];
        const int jl = tid >> 4, sub = tid & 15;
        const int j = (b - 168) * 16 + jl;
        float s = 0.f;
        for (int i = 0; i < 64; ++i) {
            const int k = sub * 64 + i;
            s += beta[k] * W1[j * 1024 + k];
        }
        red[tid] = s;
        __syncthreads();
        if (sub == 0) {
            float t = 0.f;
            for (int p = 0; p < 16; ++p) t += red[jl * 16 + p];
            ((float*)(wsb + WS_B1P))[j] = b1[j] + t;
        }
    } else if (b < 192) {                  // c_t for 64 tiles (8 per block)
        const int t8 = (b - 184) * 8 + (tid >> 5), l32 = tid & 31;
        float s = 0.f;
        for (int i = 0; i < 32; ++i) {
            const int k = l32 * 32 + i;
            const float d = dirs[t8 * 1024 + k];
            s += beta[k] * (float)((d > 0.f) - (d < 0.f));
        }
        s += __shfl_xor(s, 1); s += __shfl_xor(s, 2); s += __shfl_xor(s, 4);
        s += __shfl_xor(s, 8); s += __shfl_xor(s, 16);
        if (l32 == 0) ((float*)(wsb + WS_CT))[t8] = s;
    } else if (b == 192) {                 // c for 8 csig cols
        const int c = tid >> 5, l32 = tid & 31;
        float s = 0.f;
        for (int i = 0; i < 32; ++i) {
            const int k = l32 * 32 + i;
            int ss = 0;
            for (int t = 0; t < 8; ++t) {
                const float d = dirs[(c * 8 + t) * 1024 + k];
                ss += (d > 0.f) - (d < 0.f);
            }
            s += beta[k] * (float)((ss > 0) - (ss < 0));
        }
        s += __shfl_xor(s, 1); s += __shfl_xor(s, 2); s += __shfl_xor(s, 4);
        s += __shfl_xor(s, 8); s += __shfl_xor(s, 16);
        if (l32 == 0) ((float*)(wsb + WS_CT))[64 + c] = s;
    } else {                               // counts + pad of c
        if (tid < 64) ((unsigned*)(wsb + WS_CNT))[tid] = 0u;
        else if (tid < 72) ((float*)(wsb + WS_CT))[72 + (tid - 64)] = 0.f;
    }
}

// ---------------- main kernel ----------------
template <int USET, int NT, int CT0>
__device__ __forceinline__ void loadB(const char* __restrict__ wsb,
                                      const float* __restrict__ W1,
                                      const float* __restrict__ dirs,
                                      const float* __restrict__ gamma,
                                      int ks, int ln, f16x8* bh, f16x8* bl) {
    if (USET) {
        const char* ph = wsb + WS_FH + ((size_t)((CT0 * 32 + ks) * 64 + ln)) * 16;
        const char* pl = wsb + WS_FL + ((size_t)((CT0 * 32 + ks) * 64 + ln)) * 16;
#pragma unroll
        for (int t = 0; t < NT; ++t) {
            bh[t] = *(const f16x8*)(ph + t * 32 * 64 * 16);
            bl[t] = *(const f16x8*)(pl + t * 32 * 64 * 16);
        }
    } else {
        const int c16 = ln & 15, kb = ks * 32 + ((ln >> 4) << 3);
        float g[8];
#pragma unroll
        for (int i = 0; i < 8; ++i) g[i] = gamma[kb + i];
#pragma unroll
        for (int t = 0; t < NT; ++t) {
            const int ct = CT0 + t;
#pragma unroll
            for (int i = 0; i < 8; ++i) {
                const int k = kb + i;
                float v;
                if (ct < 16) {
                    v = g[i] * W1[(ct * 16 + c16) * 1024 + k];
                } else if (ct < 20) {
                    const float d = dirs[((ct - 16) * 16 + c16) * 1024 + k];
                    v = g[i] * (float)((d > 0.f) - (d < 0.f));
                } else {
                    if (c16 < 8) {
                        int s = 0;
                        for (int tt = 0; tt < 8; ++tt) {
                            const float d = dirs[(c16 * 8 + tt) * 1024 + k];
                            s += (d > 0.f) - (d < 0.f);
                        }
                        v = g[i] * (float)((s > 0) - (s < 0));
                    } else v = 0.f;
                }
                const _Float16 hh = (_Float16)v;
                bh[t][i] = hh; bl[t][i] = (_Float16)(v - (float)hh);
            }
        }
    }
}

template <int NT>
__device__ __forceinline__ void mfma3(const f16x8& ah, const f16x8& al,
                                      const f16x8* bh, const f16x8* bl, f32x4* acc) {
#pragma unroll
    for (int t = 0; t < NT; ++t)
        acc[t] = __builtin_amdgcn_mfma_f32_16x16x32_f16(ah, bh[t], acc[t], 0, 0, 0);
#pragma unroll
    for (int t = 0; t < NT; ++t)
        acc[t] = __builtin_amdgcn_mfma_f32_16x16x32_f16(ah, bl[t], acc[t], 0, 0, 0);
#pragma unroll
    for (int t = 0; t < NT; ++t)
        acc[t] = __builtin_amdgcn_mfma_f32_16x16x32_f16(al, bh[t], acc[t], 0, 0, 0);
}

template <int USET, int NT, int CT0>
__device__ __forceinline__ void runM(const _Float16* __restrict__ xh,
                                     const _Float16* __restrict__ xl,
                                     const char* __restrict__ wsb,
                                     const float* __restrict__ W1,
                                     const float* __restrict__ dirs,
                                     const float* __restrict__ gamma,
                                     const float* __restrict__ W2,
                                     int wv, int ln,
                                     float (*scores)[84], float (*part)[32][2]) {
    const int rt = wv >> 2, r16 = ln & 15;
    const int kofs = (ln >> 4) << 3, asw = (r16 & 7) << 3;
    const int arow = rt * 16 + r16;
    const float* b1p = (const float*)(wsb + WS_B1P);
    const float* ctv = (const float*)(wsb + WS_CT);

    f16x8 bh0[NT], bl0[NT], bh1[NT], bl1[NT], ah0, al0, ah1, al1;
    f32x4 acc[NT];
#pragma unroll
    for (int t = 0; t < NT; ++t) acc[t] = (f32x4){0.f, 0.f, 0.f, 0.f};

#define LDA(KS, AH, AL) { const int aidx = arow * 1024 + (((KS) * 32 + kofs) ^ asw); \
                          AH = *(const f16x8*)&xh[aidx]; AL = *(const f16x8*)&xl[aidx]; }

    loadB<USET, NT, CT0>(wsb, W1, dirs, gamma, 0, ln, bh0, bl0);
    LDA(0, ah0, al0);
    for (int ks = 0; ks < 32; ks += 2) {
        loadB<USET, NT, CT0>(wsb, W1, dirs, gamma, ks + 1, ln, bh1, bl1);
        LDA(ks + 1, ah1, al1);
        __builtin_amdgcn_s_barrier();
        mfma3<NT>(ah0, al0, bh0, bl0, acc);
        if (ks + 2 < 32) {
            loadB<USET, NT, CT0>(wsb, W1, dirs, gamma, ks + 2, ln, bh0, bl0);
            LDA(ks + 2, ah0, al0);
        }
        __builtin_amdgcn_s_barrier();
        mfma3<NT>(ah1, al1, bh1, bl1, acc);
    }
#undef LDA

    // epilogue
    float p0s[4] = {0.f, 0.f, 0.f, 0.f}, p1s[4] = {0.f, 0.f, 0.f, 0.f};
#pragma unroll
    for (int t = 0; t < NT; ++t) {
        const int ct = CT0 + t;
        if (ct < 16) {
            const int col = ct * 16 + r16;
            const float b1c = b1p[col], w20 = W2[col], w21 = W2[256 + col];
#pragma unroll
            for (int reg = 0; reg < 4; ++reg) {
                const float h = acc[t][reg] + b1c;
                const float gl = 0.5f * h * (1.f + erff(h * 0.70710678118654752f));
                p0s[reg] += gl * w20; p1s[reg] += gl * w21;
            }
        } else {
            const int sc = (ct - 16) * 16 + r16;
            const float cadd = ctv[sc];
#pragma unroll
            for (int reg = 0; reg < 4; ++reg)
                scores[rt * 16 + (ln >> 4) * 4 + reg][sc] = acc[t][reg] + cadd;
        }
    }
    if (CT0 < 16) {
#pragma unroll
        for (int reg = 0; reg < 4; ++reg) {
            float a0 = p0s[reg], a1 = p1s[reg];
            a0 += __shfl_xor(a0, 1); a0 += __shfl_xor(a0, 2);
            a0 += __shfl_xor(a0, 4); a0 += __shfl_xor(a0, 8);
            a1 += __shfl_xor(a1, 1); a1 += __shfl_xor(a1, 2);
            a1 += __shfl_xor(a1, 4); a1 += __shfl_xor(a1, 8);
            if (r16 == 0) {
                const int row = rt * 16 + (ln >> 4) * 4 + reg;
                part[wv][row][0] = a0; part[wv][row][1] = a1;
            }
        }
    }
}

template <int USET>
__launch_bounds__(BT, 2)
__global__ void main_kernel(const float* __restrict__ x,
                            const float* __restrict__ gamma,
                            const float* __restrict__ beta,
                            const float* __restrict__ W1,
                            const float* __restrict__ b1,
                            const float* __restrict__ W2,
                            const float* __restrict__ b2,
                            const float* __restrict__ spline,
                            const float* __restrict__ sscale,
                            const float* __restrict__ dirs,
                            const float* __restrict__ oscale,
                            float* __restrict__ out,
                            float* __restrict__ out_tile,
                            float* __restrict__ out_comp,
                            char* __restrict__ wsb) {
    __shared__ __align__(16) _Float16 xh[ROWS * 1024];
    __shared__ __align__(16) _Float16 xl[ROWS * 1024];
    __shared__ float scores[ROWS][84];
    __shared__ float part[8][ROWS][2];
    __shared__ float mu_s[ROWS], sstd_s[ROWS];
    __shared__ float comp_ab[ROWS][2], sval_s[ROWS];
    __shared__ int   tidx_s[ROWS];

    const int tid = threadIdx.x, wv = tid >> 6, ln = tid & 63;
    const int row0 = blockIdx.x * ROWS;

    // ---------- phase 1: LayerNorm stats; x-hat = (x-mu)*rstd -> f16 hi/lo LDS ----------
    for (int q = 0; q < 4; ++q) {
        const int rl = wv * 4 + q;
        const float4* xp = (const float4*)(x + (size_t)(row0 + rl) * D_MODEL);
        float4 xv[4];
        float s = 0.f;
#pragma unroll
        for (int i = 0; i < 4; ++i) {
            xv[i] = xp[ln + 64 * i];
            s += xv[i].x + xv[i].y + xv[i].z + xv[i].w;
        }
#pragma unroll
        for (int o = 1; o < 64; o <<= 1) s += __shfl_xor(s, o);
        const float mu = s * (1.f / 1024.f);
        float v = 0.f;
#pragma unroll
        for (int i = 0; i < 4; ++i) {
            float dx;
            dx = xv[i].x - mu; v += dx * dx;
            dx = xv[i].y - mu; v += dx * dx;
            dx = xv[i].z - mu; v += dx * dx;
            dx = xv[i].w - mu; v += dx * dx;
        }
#pragma unroll
        for (int o = 1; o < 64; o <<= 1) v += __shfl_xor(v, o);
        const float sstd = sqrtf(v * (1.f / 1024.f) + EPS_LN);
        const float rstd = 1.f / sstd;
        if (ln == 0) { mu_s[rl] = mu; sstd_s[rl] = sstd; }
        const int sw = (rl & 7) << 3;
#pragma unroll
        for (int i = 0; i < 4; ++i) {
            const float o0 = (xv[i].x - mu) * rstd, o1 = (xv[i].y - mu) * rstd;
            const float o2 = (xv[i].z - mu) * rstd, o3 = (xv[i].w - mu) * rstd;
            f16x4 hv, lv;
            _Float16 t0 = (_Float16)o0; hv[0] = t0; lv[0] = (_Float16)(o0 - (float)t0);
            _Float16 t1 = (_Float16)o1; hv[1] = t1; lv[1] = (_Float16)(o1 - (float)t1);
            _Float16 t2 = (_Float16)o2; hv[2] = t2; lv[2] = (_Float16)(o2 - (float)t2);
            _Float16 t3 = (_Float16)o3; hv[3] = t3; lv[3] = (_Float16)(o3 - (float)t3);
            const int k0 = 4 * (ln + 64 * i);
            const int idx = rl * 1024 + (k0 ^ sw);
            *(f16x4*)&xh[idx] = hv;
            *(f16x4*)&xl[idx] = lv;
        }
    }
    __syncthreads();

    // ---------- phase M ----------
    const int cg = wv & 3;
    if (cg == 0)      runM<USET, 6, 0 >(xh, xl, wsb, W1, dirs, gamma, W2, wv, ln, scores, part);
    else if (cg == 1) runM<USET, 5, 6 >(xh, xl, wsb, W1, dirs, gamma, W2, wv, ln, scores, part);
    else if (cg == 2) runM<USET, 5, 11>(xh, xl, wsb, W1, dirs, gamma, W2, wv, ln, scores, part);
    else              runM<USET, 5, 16>(xh, xl, wsb, W1, dirs, gamma, W2, wv, ln, scores, part);
    __syncthreads();

    // ---------- selection (tid<32) and comp finalize (tid 64..127) ----------
    unsigned* cntp = (unsigned*)(wsb + WS_CNT);
    if (tid < ROWS) {
        const int r = tid;
        int bc = 0; float bs = scores[r][64];
#pragma unroll
        for (int c = 1; c < 8; ++c) { const float v = scores[r][64 + c]; if (v > bs) { bs = v; bc = c; } }
        int bt = 0; float ts = scores[r][bc * 8];
#pragma unroll
        for (int p = 1; p < 8; ++p) { const float v = scores[r][bc * 8 + p]; if (v > ts) { ts = v; bt = p; } }
        const int ti = bc * 8 + bt;
        tidx_s[r] = ti;
        atomicAdd(&cntp[ti], 1u);
        out_tile[row0 + r] = (float)ti;
    } else if (tid >= 64 && tid < 64 + 2 * ROWS) {
        const int r = (tid - 64) >> 1, cc = tid & 1;
        const int rt = r >> 4;
        float s = part[rt * 4 + 0][r][cc] + part[rt * 4 + 1][r][cc] + part[rt * 4 + 2][r][cc] + b2[cc];
        s = tanhf(s);
        comp_ab[r][cc] = s;
        out_comp[(size_t)(row0 + r) * 2 + cc] = s;
    }
    __syncthreads();

    // ---------- spline lookup ----------
    if (tid < ROWS) {
        const int r = tid;
        const float a = comp_ab[r][0], b = comp_ab[r][1];
        int ia = (int)((a + 1.0f) / 2.0f * 16.0f);
        int ib = (int)((b + 1.0f) / 2.0f * 16.0f);
        ia = min(max(ia, 0), 15); ib = min(max(ib, 0), 15);
        const int ti = tidx_s[r];
        const float* cp = spline + ((ti * 16 + ia) * 16 + ib) * 3;
        float c0 = cp[0], c1 = cp[1], c2 = cp[2];
        c0 = (c0 > 0.3f) ? 1.f : ((c0 < -0.3f) ? -1.f : 0.f);
        c1 = (c1 > 0.3f) ? 1.f : ((c1 < -0.3f) ? -1.f : 0.f);
        c2 = (c2 > 0.3f) ? 1.f : ((c2 < -0.3f) ? -1.f : 0.f);
        const float la = (a + 1.0f - (float)ia * 0.125f) * 8.0f;
        const float lb = (b + 1.0f - (float)ib * 0.125f) * 8.0f;
        sval_s[r] = (c0 + c1 * la + c2 * lb) * sscale[ti];
    }
    __syncthreads();

    // ---------- phase 8: out = x + output_scale * sval * directions[tile] ----------
    const float os = oscale[0];
    for (int q = 0; q < 4; ++q) {
        const int rl = wv * 4 + q, row = row0 + rl;
        const int ti = tidx_s[rl];
        const float s = sval_s[rl] * os;
        const float mu = mu_s[rl], sd = sstd_s[rl];
        const int sw = (rl & 7) << 3;
        const float4* dp = (const float4*)(dirs + (size_t)ti * D_MODEL);
        float4* op = (float4*)(out + (size_t)row * D_MODEL);
#pragma unroll
        for (int i = 0; i < 4; ++i) {
            const int k0 = 4 * (ln + 64 * i);
            const int idx = rl * 1024 + (k0 ^ sw);
            const f16x4 hv = *(const f16x4*)&xh[idx];
            const f16x4 lv = *(const f16x4*)&xl[idx];
            const float4 dv = dp[ln + 64 * i];
            float4 o4;
            o4.x = ((float)hv[0] + (float)lv[0]) * sd + mu + s * dv.x;
            o4.y = ((float)hv[1] + (float)lv[1]) * sd + mu + s * dv.y;
            o4.z = ((float)hv[2] + (float)lv[2]) * sd + mu + s * dv.z;
            o4.w = ((float)hv[3] + (float)lv[3]) * sd + mu + s * dv.w;
            op[ln + 64 * i] = o4;
        }
    }
}

__global__ void bal_kernel(const unsigned* __restrict__ counts, float* __restrict__ ob) {
    const int t = threadIdx.x;
    const float d = (float)counts[t] - 512.0f;
    float v = d * d;
#pragma unroll
    for (int o = 1; o < 64; o <<= 1) v += __shfl_xor(v, o);
    if (t == 0) ob[0] = (v * (1.f / 64.f)) / 262144.0f * 0.01f;
}

extern "C" void kernel_launch(void* const* d_in, const int* in_sizes, int n_in,
                              void* d_out, int out_size, void* d_ws, size_t ws_size,
                              hipStream_t stream) {
    const float* x      = (const float*)d_in[0];
    const float* gamma  = (const float*)d_in[1];
    const float* beta   = (const float*)d_in[2];
    const float* W1     = (const float*)d_in[3];
    const float* b1     = (const float*)d_in[4];
    const float* W2     = (const float*)d_in[5];
    const float* b2     = (const float*)d_in[6];
    const float* spline = (const float*)d_in[7];
    const float* sscale = (const float*)d_in[8];
    const float* dirs   = (const float*)d_in[9];
    const float* oscale = (const float*)d_in[10];

    const int nrows = in_sizes[0] / D_MODEL;          // 32768
    float* out      = (float*)d_out;
    float* out_tile = out + (size_t)nrows * D_MODEL;
    float* out_comp = out_tile + nrows;
    float* out_bal  = out_comp + (size_t)nrows * 2;

    char* wsb = (char*)d_ws;
    const int useT = (ws_size >= (size_t)WS_NEED) ? 1 : 0;

    prep_kernel<<<194, 256, 0, stream>>>(W1, dirs, gamma, beta, b1, wsb, useT);
    if (useT)
        main_kernel<1><<<nrows / ROWS, BT, 0, stream>>>(x, gamma, beta, W1, b1, W2, b2,
                                                        spline, sscale, dirs, oscale,
                                                        out, out_tile, out_comp, wsb);
    else
        main_kernel<0><<<nrows / ROWS, BT, 0, stream>>>(x, gamma, beta, W1, b1, W2, b2,
                                                        spline, sscale, dirs, oscale,
                                                        out, out_tile, out_comp, wsb);
    bal_kernel<<<1, 64, 0, stream>>>((const unsigned*)(wsb + WS_CNT), out_bal);
}

// Round 4
// 185.273 us; speedup vs baseline: 4.4396x; 1.2438x over previous
//
#include <hip/hip_runtime.h>

#define D_MODEL 1024
#define ROWS    32      // rows per block
#define BT      512     // threads per block (8 waves)
#define EPS_LN  1e-5f

typedef _Float16 f16x8 __attribute__((ext_vector_type(8)));
typedef _Float16 f16x4 __attribute__((ext_vector_type(4)));
typedef float    f32x4 __attribute__((ext_vector_type(4)));

// ---- workspace layout (bytes) ----
#define WS_CNT   0                        // u32[64]   histogram
#define WS_B1P   256                      // f32[256]  b1' = b1 + beta @ W1^T
#define WS_CT    1280                     // f32[80]   score offsets (beta dot sig/csig)
#define WS_FH    4096                     // f16x8 [21][32][64]  gamma-folded B hi
#define WS_FL    (4096 + 688128)          // f16x8 [21][32][64]  gamma-folded B lo
#define WS_NEED  (4096 + 2 * 688128)

// tiles 0..15 : W1' columns (16 cols each)   -> gelu/W2 path
// tiles 16..19: gamma*sign(dirs) (64 tiles)  -> tile scores
// tile  20    : gamma*csig (8 cols used)     -> cluster scores

__global__ void prep_kernel(const float* __restrict__ W1,
                            const float* __restrict__ dirs,
                            const float* __restrict__ gamma,
                            const float* __restrict__ beta,
                            const float* __restrict__ b1,
                            char* __restrict__ wsb, int useT) {
    const int b = blockIdx.x, tid = threadIdx.x;
    if (b < 168) {                         // B fragments (21 x 32 x 64 lanes)
        if (!useT) return;
        const int gid = b * 256 + tid;
        const int ct = gid >> 11, ks = (gid >> 6) & 31, l = gid & 63;
        const int c16 = l & 15, kb = ks * 32 + ((l >> 4) << 3);
        f16x8 h, lo;
#pragma unroll
        for (int i = 0; i < 8; ++i) {
            const int k = kb + i;
            const float g = gamma[k];
            float v;
            if (ct < 16) {
                v = g * W1[(ct * 16 + c16) * 1024 + k];
            } else if (ct < 20) {
                const float d = dirs[((ct - 16) * 16 + c16) * 1024 + k];
                v = g * (float)((d > 0.f) - (d < 0.f));
            } else {
                if (c16 < 8) {
                    int s = 0;
                    for (int t = 0; t < 8; ++t) {
                        const float d = dirs[(c16 * 8 + t) * 1024 + k];
                        s += (d > 0.f) - (d < 0.f);
                    }
                    v = g * (float)((s > 0) - (s < 0));
                } else v = 0.f;
            }
            const _Float16 hh = (_Float16)v;
            h[i] = hh; lo[i] = (_Float16)(v - (float)hh);
        }
        *(f16x8*)(wsb + WS_FH + (size_t)gid * 16) = h;
        *(f16x8*)(wsb + WS_FL + (size_t)gid * 16) = lo;
    } else if (b < 184) {                  // b1' (16 cols per block)
        __shared__ float red[256];
        const int jl = tid >> 4, sub = tid & 15;
        const int j = (b - 168) * 16 + jl;
        float s = 0.f;
        for (int i = 0; i < 64; ++i) {
            const int k = sub * 64 + i;
            s += beta[k] * W1[j * 1024 + k];
        }
        red[tid] = s;
        __syncthreads();
        if (sub == 0) {
            float t = 0.f;
            for (int p = 0; p < 16; ++p) t += red[jl * 16 + p];
            ((float*)(wsb + WS_B1P))[j] = b1[j] + t;
        }
    } else if (b < 192) {                  // c_t for 64 tiles (8 per block)
        const int t8 = (b - 184) * 8 + (tid >> 5), l32 = tid & 31;
        float s = 0.f;
        for (int i = 0; i < 32; ++i) {
            const int k = l32 * 32 + i;
            const float d = dirs[t8 * 1024 + k];
            s += beta[k] * (float)((d > 0.f) - (d < 0.f));
        }
        s += __shfl_xor(s, 1); s += __shfl_xor(s, 2); s += __shfl_xor(s, 4);
        s += __shfl_xor(s, 8); s += __shfl_xor(s, 16);
        if (l32 == 0) ((float*)(wsb + WS_CT))[t8] = s;
    } else if (b == 192) {                 // c for 8 csig cols
        const int c = tid >> 5, l32 = tid & 31;
        float s = 0.f;
        for (int i = 0; i < 32; ++i) {
            const int k = l32 * 32 + i;
            int ss = 0;
            for (int t = 0; t < 8; ++t) {
                const float d = dirs[(c * 8 + t) * 1024 + k];
                ss += (d > 0.f) - (d < 0.f);
            }
            s += beta[k] * (float)((ss > 0) - (ss < 0));
        }
        s += __shfl_xor(s, 1); s += __shfl_xor(s, 2); s += __shfl_xor(s, 4);
        s += __shfl_xor(s, 8); s += __shfl_xor(s, 16);
        if (l32 == 0) ((float*)(wsb + WS_CT))[64 + c] = s;
    } else {                               // counts + pad of score offsets
        if (tid < 64) ((unsigned*)(wsb + WS_CNT))[tid] = 0u;
        else if (tid < 72) ((float*)(wsb + WS_CT))[72 + (tid - 64)] = 0.f;
    }
}

// ---- B-fragment fetch (fast: ws frags; slow: direct from f32) ----
template <int USET, int NT, int CT0>
__device__ __forceinline__ void loadB(const char* __restrict__ wsb,
                                      const float* __restrict__ W1,
                                      const float* __restrict__ dirs,
                                      const float* __restrict__ gamma,
                                      int ks, int ln, f16x8* bh, f16x8* bl) {
    if (USET) {
        const size_t fo = ((size_t)((CT0 * 32 + ks) * 64 + ln)) * 16;
#pragma unroll
        for (int t = 0; t < NT; ++t) {
            bh[t] = *(const f16x8*)(wsb + WS_FH + fo + (size_t)t * 32 * 64 * 16);
            bl[t] = *(const f16x8*)(wsb + WS_FL + fo + (size_t)t * 32 * 64 * 16);
        }
    } else {
        const int c16 = ln & 15, kb = ks * 32 + ((ln >> 4) << 3);
        float g[8];
#pragma unroll
        for (int i = 0; i < 8; ++i) g[i] = gamma[kb + i];
#pragma unroll
        for (int t = 0; t < NT; ++t) {
            const int ct = CT0 + t;
#pragma unroll
            for (int i = 0; i < 8; ++i) {
                const int k = kb + i;
                float v;
                if (ct < 16) {
                    v = g[i] * W1[(ct * 16 + c16) * 1024 + k];
                } else if (ct < 20) {
                    const float d = dirs[((ct - 16) * 16 + c16) * 1024 + k];
                    v = g[i] * (float)((d > 0.f) - (d < 0.f));
                } else {
                    if (c16 < 8) {
                        int s = 0;
                        for (int tt = 0; tt < 8; ++tt) {
                            const float d = dirs[(c16 * 8 + tt) * 1024 + k];
                            s += (d > 0.f) - (d < 0.f);
                        }
                        v = g[i] * (float)((s > 0) - (s < 0));
                    } else v = 0.f;
                }
                const _Float16 hh = (_Float16)v;
                bh[t][i] = hh; bl[t][i] = (_Float16)(v - (float)hh);
            }
        }
    }
}

template <int NT>
__device__ __forceinline__ void mfma6(const f16x8 (&a)[2][2], const f16x8* bh,
                                      const f16x8* bl, f32x4 (*acc)[2]) {
    __builtin_amdgcn_s_setprio(1);
#pragma unroll
    for (int t = 0; t < NT; ++t) {
        acc[t][0] = __builtin_amdgcn_mfma_f32_16x16x32_f16(a[0][0], bh[t], acc[t][0], 0, 0, 0);
        acc[t][1] = __builtin_amdgcn_mfma_f32_16x16x32_f16(a[1][0], bh[t], acc[t][1], 0, 0, 0);
    }
#pragma unroll
    for (int t = 0; t < NT; ++t) {
        acc[t][0] = __builtin_amdgcn_mfma_f32_16x16x32_f16(a[0][0], bl[t], acc[t][0], 0, 0, 0);
        acc[t][1] = __builtin_amdgcn_mfma_f32_16x16x32_f16(a[1][0], bl[t], acc[t][1], 0, 0, 0);
    }
#pragma unroll
    for (int t = 0; t < NT; ++t) {
        acc[t][0] = __builtin_amdgcn_mfma_f32_16x16x32_f16(a[0][1], bh[t], acc[t][0], 0, 0, 0);
        acc[t][1] = __builtin_amdgcn_mfma_f32_16x16x32_f16(a[1][1], bh[t], acc[t][1], 0, 0, 0);
    }
    __builtin_amdgcn_s_setprio(0);
}

// each wave owns NT column-tiles for BOTH row-tiles (32 rows); no in-loop barriers
template <int USET, int NT, int CT0>
__device__ __forceinline__ void runM(const _Float16* __restrict__ xh,
                                     const _Float16* __restrict__ xl,
                                     const char* __restrict__ wsb,
                                     const float* __restrict__ W1,
                                     const float* __restrict__ dirs,
                                     const float* __restrict__ gamma,
                                     const float* __restrict__ W2,
                                     int wv, int ln,
                                     float (*scores)[84], float (*part)[32][2]) {
    const int r16 = ln & 15, kgrp = ln >> 4;
    const int kofs = kgrp << 3, asw = (r16 & 7) << 3;
    const float* b1p = (const float*)(wsb + WS_B1P);
    const float* ctv = (const float*)(wsb + WS_CT);

    f32x4 acc[NT][2];
#pragma unroll
    for (int t = 0; t < NT; ++t) {
        acc[t][0] = (f32x4){0.f, 0.f, 0.f, 0.f};
        acc[t][1] = (f32x4){0.f, 0.f, 0.f, 0.f};
    }
    f16x8 bh0[NT], bl0[NT], bh1[NT], bl1[NT];
    f16x8 a0[2][2], a1[2][2];

#define LDA2(KS, A) { const int cc_ = (((KS) * 32 + kofs) ^ asw); \
                      const int i0_ = r16 * 1024 + cc_, i1_ = (16 + r16) * 1024 + cc_; \
                      A[0][0] = *(const f16x8*)&xh[i0_]; A[0][1] = *(const f16x8*)&xl[i0_]; \
                      A[1][0] = *(const f16x8*)&xh[i1_]; A[1][1] = *(const f16x8*)&xl[i1_]; }

    loadB<USET, NT, CT0>(wsb, W1, dirs, gamma, 0, ln, bh0, bl0);
    LDA2(0, a0);
    for (int ks = 0; ks < 32; ks += 2) {
        loadB<USET, NT, CT0>(wsb, W1, dirs, gamma, ks + 1, ln, bh1, bl1);
        LDA2(ks + 1, a1);
        mfma6<NT>(a0, bh0, bl0, acc);
        if (ks + 2 < 32) {
            loadB<USET, NT, CT0>(wsb, W1, dirs, gamma, ks + 2, ln, bh0, bl0);
            LDA2(ks + 2, a0);
        }
        mfma6<NT>(a1, bh1, bl1, acc);
    }
#undef LDA2

    // epilogue: gelu+W2 partials for W1 tiles, score dump for sig tiles
    float p0s[2][4] = {{0.f,0.f,0.f,0.f},{0.f,0.f,0.f,0.f}};
    float p1s[2][4] = {{0.f,0.f,0.f,0.f},{0.f,0.f,0.f,0.f}};
#pragma unroll
    for (int t = 0; t < NT; ++t) {
        const int ct = CT0 + t;
        if (ct < 16) {
            const int col = ct * 16 + r16;
            const float b1c = b1p[col], w20 = W2[col], w21 = W2[256 + col];
#pragma unroll
            for (int rt = 0; rt < 2; ++rt)
#pragma unroll
                for (int reg = 0; reg < 4; ++reg) {
                    const float h = acc[t][rt][reg] + b1c;
                    const float gl = 0.5f * h * (1.f + erff(h * 0.70710678118654752f));
                    p0s[rt][reg] += gl * w20; p1s[rt][reg] += gl * w21;
                }
        } else {
            const int sc = (ct - 16) * 16 + r16;
            const float cadd = ctv[sc];
#pragma unroll
            for (int rt = 0; rt < 2; ++rt)
#pragma unroll
                for (int reg = 0; reg < 4; ++reg)
                    scores[rt * 16 + kgrp * 4 + reg][sc] = acc[t][rt][reg] + cadd;
        }
    }
    if (CT0 < 16) {
#pragma unroll
        for (int rt = 0; rt < 2; ++rt)
#pragma unroll
            for (int reg = 0; reg < 4; ++reg) {
                float v0 = p0s[rt][reg], v1 = p1s[rt][reg];
                v0 += __shfl_xor(v0, 1); v0 += __shfl_xor(v0, 2);
                v0 += __shfl_xor(v0, 4); v0 += __shfl_xor(v0, 8);
                v1 += __shfl_xor(v1, 1); v1 += __shfl_xor(v1, 2);
                v1 += __shfl_xor(v1, 4); v1 += __shfl_xor(v1, 8);
                if (r16 == 0) {
                    const int row = rt * 16 + kgrp * 4 + reg;
                    part[wv][row][0] = v0; part[wv][row][1] = v1;
                }
            }
    }
}

template <int USET>
__launch_bounds__(BT, 2)
__global__ void main_kernel(const float* __restrict__ x,
                            const float* __restrict__ gamma,
                            const float* __restrict__ beta,
                            const float* __restrict__ W1,
                            const float* __restrict__ b1,
                            const float* __restrict__ W2,
                            const float* __restrict__ b2,
                            const float* __restrict__ spline,
                            const float* __restrict__ sscale,
                            const float* __restrict__ dirs,
                            const float* __restrict__ oscale,
                            float* __restrict__ out,
                            float* __restrict__ out_tile,
                            float* __restrict__ out_comp,
                            char* __restrict__ wsb) {
    __shared__ __align__(16) _Float16 xh[ROWS * 1024];
    __shared__ __align__(16) _Float16 xl[ROWS * 1024];
    __shared__ float scores[ROWS][84];
    __shared__ float part[8][ROWS][2];
    __shared__ float mu_s[ROWS], sstd_s[ROWS];
    __shared__ float comp_ab[ROWS][2], sval_s[ROWS];
    __shared__ int   tidx_s[ROWS];

    const int tid = threadIdx.x, wv = tid >> 6, ln = tid & 63;
    const int row0 = blockIdx.x * ROWS;

    // ---------- phase 1: LayerNorm stats; x-hat = (x-mu)*rstd -> f16 hi/lo LDS ----------
    for (int q = 0; q < 4; ++q) {
        const int rl = wv * 4 + q;
        const float4* xp = (const float4*)(x + (size_t)(row0 + rl) * D_MODEL);
        float4 xv[4];
        float s = 0.f;
#pragma unroll
        for (int i = 0; i < 4; ++i) {
            xv[i] = xp[ln + 64 * i];
            s += xv[i].x + xv[i].y + xv[i].z + xv[i].w;
        }
#pragma unroll
        for (int o = 1; o < 64; o <<= 1) s += __shfl_xor(s, o);
        const float mu = s * (1.f / 1024.f);
        float v = 0.f;
#pragma unroll
        for (int i = 0; i < 4; ++i) {
            float dx;
            dx = xv[i].x - mu; v += dx * dx;
            dx = xv[i].y - mu; v += dx * dx;
            dx = xv[i].z - mu; v += dx * dx;
            dx = xv[i].w - mu; v += dx * dx;
        }
#pragma unroll
        for (int o = 1; o < 64; o <<= 1) v += __shfl_xor(v, o);
        const float sstd = sqrtf(v * (1.f / 1024.f) + EPS_LN);
        const float rstd = 1.f / sstd;
        if (ln == 0) { mu_s[rl] = mu; sstd_s[rl] = sstd; }
        const int sw = (rl & 7) << 3;
#pragma unroll
        for (int i = 0; i < 4; ++i) {
            const float o0 = (xv[i].x - mu) * rstd, o1 = (xv[i].y - mu) * rstd;
            const float o2 = (xv[i].z - mu) * rstd, o3 = (xv[i].w - mu) * rstd;
            f16x4 hv, lv;
            _Float16 t0 = (_Float16)o0; hv[0] = t0; lv[0] = (_Float16)(o0 - (float)t0);
            _Float16 t1 = (_Float16)o1; hv[1] = t1; lv[1] = (_Float16)(o1 - (float)t1);
            _Float16 t2 = (_Float16)o2; hv[2] = t2; lv[2] = (_Float16)(o2 - (float)t2);
            _Float16 t3 = (_Float16)o3; hv[3] = t3; lv[3] = (_Float16)(o3 - (float)t3);
            const int k0 = 4 * (ln + 64 * i);
            const int idx = rl * 1024 + (k0 ^ sw);
            *(f16x4*)&xh[idx] = hv;
            *(f16x4*)&xl[idx] = lv;
        }
    }
    __syncthreads();

    // ---------- phase M: wave-owned tiles, barrier-free ----------
    if (wv == 0)      runM<USET, 3, 0 >(xh, xl, wsb, W1, dirs, gamma, W2, wv, ln, scores, part);
    else if (wv == 1) runM<USET, 3, 3 >(xh, xl, wsb, W1, dirs, gamma, W2, wv, ln, scores, part);
    else if (wv == 2) runM<USET, 3, 6 >(xh, xl, wsb, W1, dirs, gamma, W2, wv, ln, scores, part);
    else if (wv == 3) runM<USET, 3, 9 >(xh, xl, wsb, W1, dirs, gamma, W2, wv, ln, scores, part);
    else if (wv == 4) runM<USET, 3, 12>(xh, xl, wsb, W1, dirs, gamma, W2, wv, ln, scores, part);
    else if (wv == 5) runM<USET, 2, 15>(xh, xl, wsb, W1, dirs, gamma, W2, wv, ln, scores, part);
    else if (wv == 6) runM<USET, 2, 17>(xh, xl, wsb, W1, dirs, gamma, W2, wv, ln, scores, part);
    else              runM<USET, 2, 19>(xh, xl, wsb, W1, dirs, gamma, W2, wv, ln, scores, part);
    __syncthreads();

    // ---------- selection (tid<32) and comp finalize (tid 64..127) ----------
    unsigned* cntp = (unsigned*)(wsb + WS_CNT);
    if (tid < ROWS) {
        const int r = tid;
        int bc = 0; float bs = scores[r][64];
#pragma unroll
        for (int c = 1; c < 8; ++c) { const float v = scores[r][64 + c]; if (v > bs) { bs = v; bc = c; } }
        int bt = 0; float ts = scores[r][bc * 8];
#pragma unroll
        for (int p = 1; p < 8; ++p) { const float v = scores[r][bc * 8 + p]; if (v > ts) { ts = v; bt = p; } }
        const int ti = bc * 8 + bt;
        tidx_s[r] = ti;
        atomicAdd(&cntp[ti], 1u);
        out_tile[row0 + r] = (float)ti;
    } else if (tid >= 64 && tid < 64 + 2 * ROWS) {
        const int r = (tid - 64) >> 1, cc = tid & 1;
        float s = part[0][r][cc] + part[1][r][cc] + part[2][r][cc] +
                  part[3][r][cc] + part[4][r][cc] + part[5][r][cc] + b2[cc];
        s = tanhf(s);
        comp_ab[r][cc] = s;
        out_comp[(size_t)(row0 + r) * 2 + cc] = s;
    }
    __syncthreads();

    // ---------- spline lookup ----------
    if (tid < ROWS) {
        const int r = tid;
        const float a = comp_ab[r][0], b = comp_ab[r][1];
        int ia = (int)((a + 1.0f) / 2.0f * 16.0f);
        int ib = (int)((b + 1.0f) / 2.0f * 16.0f);
        ia = min(max(ia, 0), 15); ib = min(max(ib, 0), 15);
        const int ti = tidx_s[r];
        const float* cp = spline + ((ti * 16 + ia) * 16 + ib) * 3;
        float c0 = cp[0], c1 = cp[1], c2 = cp[2];
        c0 = (c0 > 0.3f) ? 1.f : ((c0 < -0.3f) ? -1.f : 0.f);
        c1 = (c1 > 0.3f) ? 1.f : ((c1 < -0.3f) ? -1.f : 0.f);
        c2 = (c2 > 0.3f) ? 1.f : ((c2 < -0.3f) ? -1.f : 0.f);
        const float la = (a + 1.0f - (float)ia * 0.125f) * 8.0f;
        const float lb = (b + 1.0f - (float)ib * 0.125f) * 8.0f;
        sval_s[r] = (c0 + c1 * la + c2 * lb) * sscale[ti];
    }
    __syncthreads();

    // ---------- phase 8: out = x + output_scale * sval * directions[tile] ----------
    const float os = oscale[0];
    for (int q = 0; q < 4; ++q) {
        const int rl = wv * 4 + q, row = row0 + rl;
        const int ti = tidx_s[rl];
        const float s = sval_s[rl] * os;
        const float mu = mu_s[rl], sd = sstd_s[rl];
        const int sw = (rl & 7) << 3;
        const float4* dp = (const float4*)(dirs + (size_t)ti * D_MODEL);
        float4* op = (float4*)(out + (size_t)row * D_MODEL);
#pragma unroll
        for (int i = 0; i < 4; ++i) {
            const int k0 = 4 * (ln + 64 * i);
            const int idx = rl * 1024 + (k0 ^ sw);
            const f16x4 hv = *(const f16x4*)&xh[idx];
            const f16x4 lv = *(const f16x4*)&xl[idx];
            const float4 dv = dp[ln + 64 * i];
            float4 o4;
            o4.x = ((float)hv[0] + (float)lv[0]) * sd + mu + s * dv.x;
            o4.y = ((float)hv[1] + (float)lv[1]) * sd + mu + s * dv.y;
            o4.z = ((float)hv[2] + (float)lv[2]) * sd + mu + s * dv.z;
            o4.w = ((float)hv[3] + (float)lv[3]) * sd + mu + s * dv.w;
            op[ln + 64 * i] = o4;
        }
    }
}

__global__ void bal_kernel(const unsigned* __restrict__ counts, float* __restrict__ ob) {
    const int t = threadIdx.x;
    const float d = (float)counts[t] - 512.0f;
    float v = d * d;
#pragma unroll
    for (int o = 1; o < 64; o <<= 1) v += __shfl_xor(v, o);
    if (t == 0) ob[0] = (v * (1.f / 64.f)) / 262144.0f * 0.01f;
}

extern "C" void kernel_launch(void* const* d_in, const int* in_sizes, int n_in,
                              void* d_out, int out_size, void* d_ws, size_t ws_size,
                              hipStream_t stream) {
    const float* x      = (const float*)d_in[0];
    const float* gamma  = (const float*)d_in[1];
    const float* beta   = (const float*)d_in[2];
    const float* W1     = (const float*)d_in[3];
    const float* b1     = (const float*)d_in[4];
    const float* W2     = (const float*)d_in[5];
    const float* b2     = (const float*)d_in[6];
    const float* spline = (const float*)d_in[7];
    const float* sscale = (const float*)d_in[8];
    const float* dirs   = (const float*)d_in[9];
    const float* oscale = (const float*)d_in[10];

    const int nrows = in_sizes[0] / D_MODEL;          // 32768
    float* out      = (float*)d_out;
    float* out_tile = out + (size_t)nrows * D_MODEL;
    float* out_comp = out_tile + nrows;
    float* out_bal  = out_comp + (size_t)nrows * 2;

    char* wsb = (char*)d_ws;
    const int useT = (ws_size >= (size_t)WS_NEED) ? 1 : 0;

    prep_kernel<<<194, 256, 0, stream>>>(W1, dirs, gamma, beta, b1, wsb, useT);
    if (useT)
        main_kernel<1><<<nrows / ROWS, BT, 0, stream>>>(x, gamma, beta, W1, b1, W2, b2,
                                                        spline, sscale, dirs, oscale,
                                                        out, out_tile, out_comp, wsb);
    else
        main_kernel<0><<<nrows / ROWS, BT, 0, stream>>>(x, gamma, beta, W1, b1, W2, b2,
                                                        spline, sscale, dirs, oscale,
                                                        out, out_tile, out_comp, wsb);
    bal_kernel<<<1, 64, 0, stream>>>((const unsigned*)(wsb + WS_CNT), out_bal);
}